// Round 1
// baseline (575.765 us; speedup 1.0000x reference)
//
#include <hip/hip_runtime.h>
#include <hip/hip_bf16.h>
#include <stdint.h>

// Problem constants (reference: LoRA adapter forward)
#define TOKENS   8192
#define DIM      4096
#define DIM_OUT  4096
#define LORA_R   16
#define LORA_SCALE 2.0f

typedef __bf16 bf16_t;
typedef __attribute__((ext_vector_type(8))) __bf16 bfrag;   // 8 bf16 = 4 VGPR (MFMA A/B frag)
typedef __attribute__((ext_vector_type(4))) float f32x4;    // MFMA C/D frag

// ---------------------------------------------------------------------------
// async global->LDS, 16B per lane (global_load_lds_dwordx4).
// LDS dest is wave-uniform base + lane*16; we pass the per-lane linear target
// (lane0's value is the wave base, so either HW semantic lands identically).
// ---------------------------------------------------------------------------
__device__ __forceinline__ void gload_lds16(const bf16_t* gsrc, bf16_t* ldst) {
    __builtin_amdgcn_global_load_lds(
        (const __attribute__((address_space(1))) uint32_t*)(const void*)gsrc,
        (__attribute__((address_space(3))) uint32_t*)(void*)ldst,
        16, 0, 0);
}

// ---------------------------------------------------------------------------
// Kernel 1: cast x (fp32) -> bf16, 8 elems/thread, grid-stride
// ---------------------------------------------------------------------------
__global__ void cast_x_kernel(const float* __restrict__ x, bf16_t* __restrict__ xb) {
    const int total = TOKENS * DIM / 8;
    for (int i = blockIdx.x * blockDim.x + threadIdx.x; i < total;
         i += gridDim.x * blockDim.x) {
        const float4* p = reinterpret_cast<const float4*>(x + (size_t)i * 8);
        float4 v0 = p[0], v1 = p[1];
        union { bf16_t o[8]; uint4 u; } pk;
        pk.o[0] = (bf16_t)v0.x; pk.o[1] = (bf16_t)v0.y;
        pk.o[2] = (bf16_t)v0.z; pk.o[3] = (bf16_t)v0.w;
        pk.o[4] = (bf16_t)v1.x; pk.o[5] = (bf16_t)v1.y;
        pk.o[6] = (bf16_t)v1.z; pk.o[7] = (bf16_t)v1.w;
        *reinterpret_cast<uint4*>(xb + (size_t)i * 8) = pk.u;
    }
}

// ---------------------------------------------------------------------------
// Kernel 2: Weff_t[n][k] = W[n][k] + SCALE * sum_r A[k][r]*B[r][n], cast bf16.
// N-major (= W's own layout) so the GEMM's B-operand frag loads are contiguous
// in K. One thread per 8 consecutive k of one n.
// ---------------------------------------------------------------------------
__global__ void weff_kernel(const float* __restrict__ W, const float* __restrict__ A,
                            const float* __restrict__ B, bf16_t* __restrict__ Wt) {
    int idx = blockIdx.x * blockDim.x + threadIdx.x;   // DIM_OUT*DIM/8 threads
    int n  = idx >> 9;            // DIM/8 == 512
    int k0 = (idx & 511) << 3;

    float bn[LORA_R];
#pragma unroll
    for (int r = 0; r < LORA_R; ++r) bn[r] = B[(size_t)r * DIM_OUT + n];

    const float4* wp = reinterpret_cast<const float4*>(W + (size_t)n * DIM + k0);
    float4 w0 = wp[0], w1 = wp[1];
    float wv[8] = {w0.x, w0.y, w0.z, w0.w, w1.x, w1.y, w1.z, w1.w};

    union { bf16_t o[8]; uint4 u; } pk;
#pragma unroll
    for (int j = 0; j < 8; ++j) {
        const float4* ap = reinterpret_cast<const float4*>(A + (size_t)(k0 + j) * LORA_R);
        float4 a0 = ap[0], a1 = ap[1], a2 = ap[2], a3 = ap[3];
        float ab = a0.x*bn[0] + a0.y*bn[1] + a0.z*bn[2] + a0.w*bn[3]
                 + a1.x*bn[4] + a1.y*bn[5] + a1.z*bn[6] + a1.w*bn[7]
                 + a2.x*bn[8] + a2.y*bn[9] + a2.z*bn[10]+ a2.w*bn[11]
                 + a3.x*bn[12]+ a3.y*bn[13]+ a3.z*bn[14]+ a3.w*bn[15];
        pk.o[j] = (bf16_t)(wv[j] + LORA_SCALE * ab);
    }
    *reinterpret_cast<uint4*>(Wt + (size_t)n * DIM + k0) = pk.u;
}

// ---------------------------------------------------------------------------
// Kernel 3: C[m][n] = sum_k Xb[m][k]*Wt[n][k] + bias[n]
// m97-verified structure: 128x128 tile, BK=32, 256 thr (4 waves 2x2),
// 4x4 16x16x32 bf16 MFMA frags per wave, global_load_lds w=16, 2-barrier loop.
// ---------------------------------------------------------------------------
#define BM 128
#define BN 128
#define BK 32
#define MB_BLKS (TOKENS / BM)    // 64
#define NB_BLKS (DIM_OUT / BN)   // 32

__global__ __launch_bounds__(256) void gemm_kernel(
    const bf16_t* __restrict__ Xb, const bf16_t* __restrict__ Wt,
    const float* __restrict__ bias, float* __restrict__ C)
{
    __shared__ __align__(16) bf16_t As[BM * BK];   // [128][32] row-major (m, k)
    __shared__ __align__(16) bf16_t Bs[BN * BK];   // [128][32] row-major (n, k)

    const int nwg = MB_BLKS * NB_BLKS;             // 2048, %8==0 -> bijective swizzle
    int bid = blockIdx.x;
    int swz = (bid & 7) * (nwg >> 3) + (bid >> 3); // XCD-aware remap
    int bm = swz / NB_BLKS;
    int bn = swz % NB_BLKS;

    int tid  = threadIdx.x;
    int lane = tid & 63;
    int wave = tid >> 6;
    int wr = wave >> 1, wc = wave & 1;             // wave -> 64x64 output quadrant

    // staging addresses: thread t stages LDS elements [t*8, t*8+8) of each
    // half-tile; linear LDS elem t*8 == tile (row=t/4, col=(t%4)*8), stride 32.
    const bf16_t* aSrc = Xb + (size_t)(bm * BM + (tid >> 2)) * DIM + (tid & 3) * 8;
    const bf16_t* bSrc = Wt + (size_t)(bn * BN + (tid >> 2)) * DIM + (tid & 3) * 8;
    bf16_t* aDst = As + tid * 8;
    bf16_t* bDst = Bs + tid * 8;

    f32x4 acc[4][4] = {};

    const int ar = lane & 15;             // row (A) / col (B) within 16-frag
    const int kg = (lane >> 4) * 8;       // k-slot (self-consistent A/B mapping)
    const int aoff0 = (wr * 64 + ar) * BK + kg;
    const int boff0 = (wc * 64 + ar) * BK + kg;

    for (int kt = 0; kt < DIM / BK; ++kt) {
        gload_lds16(aSrc + kt * BK,            aDst);
        gload_lds16(aSrc + 64 * DIM + kt * BK, aDst + 2048);
        gload_lds16(bSrc + kt * BK,            bDst);
        gload_lds16(bSrc + 64 * DIM + kt * BK, bDst + 2048);
        __syncthreads();   // compiler drains vmcnt before s_barrier

        bfrag af[4], bfv[4];
#pragma unroll
        for (int m = 0; m < 4; ++m)
            af[m] = *reinterpret_cast<const bfrag*>(&As[aoff0 + m * 16 * BK]);
#pragma unroll
        for (int n = 0; n < 4; ++n)
            bfv[n] = *reinterpret_cast<const bfrag*>(&Bs[boff0 + n * 16 * BK]);
#pragma unroll
        for (int m = 0; m < 4; ++m)
#pragma unroll
            for (int n = 0; n < 4; ++n)
                acc[m][n] = __builtin_amdgcn_mfma_f32_16x16x32_bf16(
                    af[m], bfv[n], acc[m][n], 0, 0, 0);
        __syncthreads();   // protect LDS before next stage
    }

    // epilogue: C/D layout (verified): row = (lane>>4)*4 + reg, col = lane&15
    int row0 = bm * BM + wr * 64 + (lane >> 4) * 4;
    int col0 = bn * BN + wc * 64 + ar;
#pragma unroll
    for (int n = 0; n < 4; ++n) {
        int c = col0 + n * 16;
        float bv = bias[c];
#pragma unroll
        for (int m = 0; m < 4; ++m) {
            int r = row0 + m * 16;
#pragma unroll
            for (int j = 0; j < 4; ++j)
                C[(size_t)(r + j) * DIM_OUT + c] = acc[m][n][j] + bv;
        }
    }
}

// ---------------------------------------------------------------------------
extern "C" void kernel_launch(void* const* d_in, const int* in_sizes, int n_in,
                              void* d_out, int out_size, void* d_ws, size_t ws_size,
                              hipStream_t stream) {
    const float* x = (const float*)d_in[0];
    const float* A = (const float*)d_in[1];
    const float* B = (const float*)d_in[2];
    const float* W = (const float*)d_in[3];
    const float* b = (const float*)d_in[4];
    float* out = (float*)d_out;

    // workspace: xb (8192*4096 bf16 = 64MB) | Wt (4096*4096 bf16 = 32MB)
    bf16_t* xb = (bf16_t*)d_ws;
    bf16_t* Wt = (bf16_t*)((char*)d_ws + (size_t)TOKENS * DIM * 2);

    cast_x_kernel<<<2048, 256, 0, stream>>>(x, xb);
    weff_kernel<<<(DIM_OUT * DIM / 8) / 256, 256, 0, stream>>>(W, A, B, Wt);
    gemm_kernel<<<MB_BLKS * NB_BLKS, 256, 0, stream>>>(xb, Wt, b, out);
}

// Round 2
// 340.331 us; speedup vs baseline: 1.6918x; 1.6918x over previous
//
#include <hip/hip_runtime.h>
#include <hip/hip_bf16.h>
#include <stdint.h>

// Problem constants (reference: LoRA adapter forward)
#define TOKENS   8192
#define DIM      4096
#define DIM_OUT  4096
#define LORA_R   16
#define LORA_SCALE 2.0f

typedef __bf16 bf16_t;
typedef __attribute__((ext_vector_type(8))) __bf16 bfrag;   // 8 bf16 = 4 VGPR (MFMA A/B frag)
typedef __attribute__((ext_vector_type(4))) float f32x4;    // MFMA C/D frag

// ---------------------------------------------------------------------------
// async global->LDS, 16B per lane (global_load_lds_dwordx4)
// ---------------------------------------------------------------------------
__device__ __forceinline__ void gload_lds16(const bf16_t* gsrc, bf16_t* ldst) {
    __builtin_amdgcn_global_load_lds(
        (const __attribute__((address_space(1))) uint32_t*)(const void*)gsrc,
        (__attribute__((address_space(3))) uint32_t*)(void*)ldst,
        16, 0, 0);
}

// ---------------------------------------------------------------------------
// Kernel 1: cast x (fp32) -> bf16, 8 elems/thread, grid-stride
// ---------------------------------------------------------------------------
__global__ void cast_x_kernel(const float* __restrict__ x, bf16_t* __restrict__ xb) {
    const int total = TOKENS * DIM / 8;
    for (int i = blockIdx.x * blockDim.x + threadIdx.x; i < total;
         i += gridDim.x * blockDim.x) {
        const float4* p = reinterpret_cast<const float4*>(x + (size_t)i * 8);
        float4 v0 = p[0], v1 = p[1];
        union { bf16_t o[8]; uint4 u; } pk;
        pk.o[0] = (bf16_t)v0.x; pk.o[1] = (bf16_t)v0.y;
        pk.o[2] = (bf16_t)v0.z; pk.o[3] = (bf16_t)v0.w;
        pk.o[4] = (bf16_t)v1.x; pk.o[5] = (bf16_t)v1.y;
        pk.o[6] = (bf16_t)v1.z; pk.o[7] = (bf16_t)v1.w;
        *reinterpret_cast<uint4*>(xb + (size_t)i * 8) = pk.u;
    }
}

// ---------------------------------------------------------------------------
// Kernel 2: Weff_t[n][k] = W[n][k] + SCALE * sum_r A[k][r]*B[r][n], cast bf16.
// 4 n x 8 k per thread: cuts A re-read traffic ~4x vs 1n x 8k.
// ---------------------------------------------------------------------------
__global__ void weff_kernel(const float* __restrict__ W, const float* __restrict__ A,
                            const float* __restrict__ B, bf16_t* __restrict__ Wt) {
    int idx = blockIdx.x * blockDim.x + threadIdx.x;   // DIM_OUT*DIM/32 threads
    int k0 = (idx & 511) << 3;          // 512 k-groups of 8
    int n0 = (idx >> 9) << 2;           // 1024 n-groups of 4

    float bn[4][16];
#pragma unroll
    for (int r = 0; r < 16; ++r) {
        float4 bv = *reinterpret_cast<const float4*>(B + (size_t)r * DIM_OUT + n0);
        bn[0][r] = bv.x; bn[1][r] = bv.y; bn[2][r] = bv.z; bn[3][r] = bv.w;
    }
    float ab[4][8];
#pragma unroll
    for (int j = 0; j < 8; ++j) {
        const float4* ap = reinterpret_cast<const float4*>(A + (size_t)(k0 + j) * LORA_R);
        float4 a0 = ap[0], a1 = ap[1], a2 = ap[2], a3 = ap[3];
        float av[16] = {a0.x,a0.y,a0.z,a0.w,a1.x,a1.y,a1.z,a1.w,
                        a2.x,a2.y,a2.z,a2.w,a3.x,a3.y,a3.z,a3.w};
#pragma unroll
        for (int n = 0; n < 4; ++n) {
            float s = 0.f;
#pragma unroll
            for (int r = 0; r < 16; ++r) s += av[r] * bn[n][r];
            ab[n][j] = s;
        }
    }
#pragma unroll
    for (int n = 0; n < 4; ++n) {
        const float4* wp = reinterpret_cast<const float4*>(W + (size_t)(n0 + n) * DIM + k0);
        float4 w0 = wp[0], w1 = wp[1];
        float wv[8] = {w0.x,w0.y,w0.z,w0.w,w1.x,w1.y,w1.z,w1.w};
        union { bf16_t o[8]; uint4 u; } pk;
#pragma unroll
        for (int j = 0; j < 8; ++j) pk.o[j] = (bf16_t)(wv[j] + LORA_SCALE * ab[n][j]);
        *reinterpret_cast<uint4*>(Wt + (size_t)(n0 + n) * DIM + k0) = pk.u;
    }
}

// ---------------------------------------------------------------------------
// Kernel 3: 256x256 8-phase GEMM (T1+T2+T3+T4+T5).
// C[m][n] = sum_k Xb[m][k]*Wt[n][k] + bias[n]
// 512 thr = 8 waves (2M x 4N); per-wave 128x64 out = acc[8][4] 16x16 frags.
// LDS: 2 dbuf x (A 256x64 + B 256x64) bf16 = 128 KiB.
// Swizzle: logical colbyte ^= (row&7)<<4  (== col-slot ^ (row&7), 16B granules)
//   - staging: linear LDS dest + inverse-swizzled global source (rule #21)
//   - ds_read: col elem = ((ks*4 + (lane>>4)) ^ (lane&7)) * 8  -> 2-way (free)
// Schedule per K-tile (buffer d), phases:
//   P0: read A[m0-3],B[n0-1] | bar | MFMA m0-3 x n0-1 | bar
//   P1: read B[n2-3]         | bar | MFMA m0-3 x n2-3 | bar
//   P2: read A[m4-7], STAGE B(next tile)->d | bar | MFMA m4-7 x n0-1 | bar
//   P3: STAGE A(next)->d     | bar | MFMA m4-7 x n2-3 | vmcnt(8) | bar
// vmcnt(8) at each tile boundary keeps the next tile's 8 loads in flight
// (never drains to 0 in the main loop). Stage-into-own-buffer is safe:
// B-region reads end at P1's barrier, A-region reads at P2's barrier.
// ---------------------------------------------------------------------------
#define BM 256
#define BN 256
#define BK 64
#define MB_BLKS (TOKENS / BM)    // 32
#define NB_BLKS (DIM_OUT / BN)   // 16
#define NT      (DIM / BK)       // 64 K-tiles
#define ITERS   (NT / 2)         // 32 double-tile iterations

#define BAR() do { __builtin_amdgcn_s_barrier(); __builtin_amdgcn_sched_barrier(0); } while (0)
#define VMWAIT_(n) asm volatile("s_waitcnt vmcnt(" #n ")" ::: "memory")
#define VMWAIT(n) VMWAIT_(n)

__global__ __launch_bounds__(512, 2) void gemm_kernel(
    const bf16_t* __restrict__ Xb, const bf16_t* __restrict__ Wt,
    const float* __restrict__ bias, float* __restrict__ C)
{
    __shared__ __align__(16) bf16_t sA[2][BM][BK];   // 64 KiB
    __shared__ __align__(16) bf16_t sB[2][BN][BK];   // 64 KiB

    const int nwg = MB_BLKS * NB_BLKS;               // 512, %8==0 -> bijective
    int bid = blockIdx.x;
    int swz = (bid & 7) * (nwg >> 3) + (bid >> 3);   // XCD-aware remap
    int bm = swz / NB_BLKS;
    int bn = swz % NB_BLKS;

    const int tid  = threadIdx.x;
    const int lane = tid & 63;
    const int wid  = tid >> 6;       // 0..7
    const int wr   = wid >> 2;       // 0..1  (M half)
    const int wc   = wid & 3;        // 0..3  (N quarter)

    // ---- staging constants (linear LDS dest, pre-swizzled global src) ----
    const int srow = tid >> 3;                       // 0..63
    const int scol = (tid & 7) * 8;                  // linear col (elems)
    const int koff = (((tid & 7) ^ ((tid >> 3) & 7)) * 8); // swizzled src col
    const bf16_t* Ag = Xb + (size_t)(bm * BM + srow) * DIM + koff;
    const bf16_t* Bg = Wt + (size_t)(bn * BN + srow) * DIM + koff;

#define STAGE_A(d, kt) do { \
    const bf16_t* s_ = Ag + (size_t)(kt) * BK; \
    bf16_t* d_ = &sA[d][srow][scol]; \
    gload_lds16(s_,                     d_); \
    gload_lds16(s_ + (size_t)64  * DIM, d_ + 64  * BK); \
    gload_lds16(s_ + (size_t)128 * DIM, d_ + 128 * BK); \
    gload_lds16(s_ + (size_t)192 * DIM, d_ + 192 * BK); \
} while (0)

#define STAGE_B(d, kt) do { \
    const bf16_t* s_ = Bg + (size_t)(kt) * BK; \
    bf16_t* d_ = &sB[d][srow][scol]; \
    gload_lds16(s_,                     d_); \
    gload_lds16(s_ + (size_t)64  * DIM, d_ + 64  * BK); \
    gload_lds16(s_ + (size_t)128 * DIM, d_ + 128 * BK); \
    gload_lds16(s_ + (size_t)192 * DIM, d_ + 192 * BK); \
} while (0)

    // ---- fragment-read constants (swizzled) ----
    const int q     = lane & 7;
    const int kslot = lane >> 4;                     // 0..3
    const int r15   = lane & 15;
    const int cK0   = ((kslot    ) ^ q) * 8;         // ks=0 col (elems)
    const int cK1   = ((kslot + 4) ^ q) * 8;         // ks=1 col (elems)
    const int arow0 = wr * 128 + r15;                // + m*16
    const int brow0 = wc * 64  + r15;                // + n*16

    f32x4 acc[8][4] = {};
    bfrag af[4][2], bf[4][2];

#define LOAD_A(d, mb) do { \
    _Pragma("unroll") \
    for (int m_ = 0; m_ < 4; ++m_) { \
        af[m_][0] = *reinterpret_cast<const bfrag*>(&sA[d][arow0 + (mb + m_) * 16][cK0]); \
        af[m_][1] = *reinterpret_cast<const bfrag*>(&sA[d][arow0 + (mb + m_) * 16][cK1]); \
    } \
} while (0)

#define LOAD_B2(d, nb) do { \
    _Pragma("unroll") \
    for (int n_ = 0; n_ < 2; ++n_) { \
        bf[nb + n_][0] = *reinterpret_cast<const bfrag*>(&sB[d][brow0 + (nb + n_) * 16][cK0]); \
        bf[nb + n_][1] = *reinterpret_cast<const bfrag*>(&sB[d][brow0 + (nb + n_) * 16][cK1]); \
    } \
} while (0)

#define MFMA_Q(mb, nb) do { \
    __builtin_amdgcn_s_setprio(1); \
    _Pragma("unroll") \
    for (int m_ = 0; m_ < 4; ++m_) \
    _Pragma("unroll") \
    for (int n_ = 0; n_ < 2; ++n_) \
    _Pragma("unroll") \
    for (int ks_ = 0; ks_ < 2; ++ks_) \
        acc[mb + m_][nb + n_] = __builtin_amdgcn_mfma_f32_16x16x32_bf16( \
            af[m_][ks_], bf[nb + n_][ks_], acc[mb + m_][nb + n_], 0, 0, 0); \
    __builtin_amdgcn_s_setprio(0); \
} while (0)

// One K-tile = 4 phases. DO_STAGE: stage tile `ktn` (A and B) into buffer d.
// VM: vmcnt immediate at the tile-boundary wait.
#define TILE_PHASES(d, ktn, DO_STAGE, VM) do { \
    /* P0 */ LOAD_A(d, 0); LOAD_B2(d, 0); BAR(); MFMA_Q(0, 0); BAR(); \
    /* P1 */ LOAD_B2(d, 2);               BAR(); MFMA_Q(0, 2); BAR(); \
    /* P2 */ LOAD_A(d, 4); if (DO_STAGE) STAGE_B(d, ktn); \
                                          BAR(); MFMA_Q(4, 0); BAR(); \
    /* P3 */ if (DO_STAGE) STAGE_A(d, ktn); \
                                          BAR(); MFMA_Q(4, 2); \
             VMWAIT(VM); BAR(); \
} while (0)

    // ---- prologue: tiles 0 and 1 into buffers 0 and 1 ----
    STAGE_A(0, 0); STAGE_B(0, 0);
    STAGE_A(1, 1); STAGE_B(1, 1);
    VMWAIT(8);          // tile 0 complete; tile 1's 8 loads stay in flight
    BAR();

    // ---- main loop: 31 iterations, 2 K-tiles each ----
    for (int it = 0; it < ITERS - 1; ++it) {
        int kt0 = 2 * it;
        TILE_PHASES(0, kt0 + 2, true, 8);
        TILE_PHASES(1, kt0 + 3, true, 8);
    }
    // ---- peeled last iteration: tiles 62, 63, no staging ----
    TILE_PHASES(0, 0, false, 0);
    TILE_PHASES(1, 0, false, 0);

    // ---- epilogue: D layout row=(lane>>4)*4+j, col=lane&15 ----
    int row0 = bm * BM + wr * 128 + (lane >> 4) * 4;
    int col0 = bn * BN + wc * 64 + r15;
#pragma unroll
    for (int n = 0; n < 4; ++n) {
        int c = col0 + n * 16;
        float bv = bias[c];
#pragma unroll
        for (int m = 0; m < 8; ++m) {
            int r = row0 + m * 16;
#pragma unroll
            for (int j = 0; j < 4; ++j)
                C[(size_t)(r + j) * DIM_OUT + c] = acc[m][n][j] + bv;
        }
    }
}

// ---------------------------------------------------------------------------
extern "C" void kernel_launch(void* const* d_in, const int* in_sizes, int n_in,
                              void* d_out, int out_size, void* d_ws, size_t ws_size,
                              hipStream_t stream) {
    const float* x = (const float*)d_in[0];
    const float* A = (const float*)d_in[1];
    const float* B = (const float*)d_in[2];
    const float* W = (const float*)d_in[3];
    const float* b = (const float*)d_in[4];
    float* out = (float*)d_out;

    // workspace: xb (8192*4096 bf16 = 64MB) | Wt (4096*4096 bf16 = 32MB)
    bf16_t* xb = (bf16_t*)d_ws;
    bf16_t* Wt = (bf16_t*)((char*)d_ws + (size_t)TOKENS * DIM * 2);

    cast_x_kernel<<<2048, 256, 0, stream>>>(x, xb);
    weff_kernel<<<(DIM_OUT * DIM / 32) / 256, 256, 0, stream>>>(W, A, B, Wt);
    gemm_kernel<<<MB_BLKS * NB_BLKS, 512, 0, stream>>>(xb, Wt, b, out);
}

// Round 3
// 329.359 us; speedup vs baseline: 1.7481x; 1.0333x over previous
//
#include <hip/hip_runtime.h>
#include <hip/hip_bf16.h>
#include <stdint.h>

// Problem constants (reference: LoRA adapter forward)
#define TOKENS   8192
#define DIM      4096
#define DIM_OUT  4096
#define LORA_R   16
#define LORA_SCALE 2.0f

typedef __bf16 bf16_t;
typedef __attribute__((ext_vector_type(8))) __bf16 bfrag;   // 8 bf16 = 4 VGPR (MFMA A/B frag)
typedef __attribute__((ext_vector_type(4))) float f32x4;    // MFMA C/D frag

// ---------------------------------------------------------------------------
// async global->LDS, 16B per lane (global_load_lds_dwordx4)
// ---------------------------------------------------------------------------
__device__ __forceinline__ void gload_lds16(const bf16_t* gsrc, bf16_t* ldst) {
    __builtin_amdgcn_global_load_lds(
        (const __attribute__((address_space(1))) uint32_t*)(const void*)gsrc,
        (__attribute__((address_space(3))) uint32_t*)(void*)ldst,
        16, 0, 0);
}

// ---------------------------------------------------------------------------
// Kernel 1: cast x (fp32) -> bf16, 8 elems/thread, grid-stride
// ---------------------------------------------------------------------------
__global__ void cast_x_kernel(const float* __restrict__ x, bf16_t* __restrict__ xb) {
    const int total = TOKENS * DIM / 8;
    for (int i = blockIdx.x * blockDim.x + threadIdx.x; i < total;
         i += gridDim.x * blockDim.x) {
        const float4* p = reinterpret_cast<const float4*>(x + (size_t)i * 8);
        float4 v0 = p[0], v1 = p[1];
        union { bf16_t o[8]; uint4 u; } pk;
        pk.o[0] = (bf16_t)v0.x; pk.o[1] = (bf16_t)v0.y;
        pk.o[2] = (bf16_t)v0.z; pk.o[3] = (bf16_t)v0.w;
        pk.o[4] = (bf16_t)v1.x; pk.o[5] = (bf16_t)v1.y;
        pk.o[6] = (bf16_t)v1.z; pk.o[7] = (bf16_t)v1.w;
        *reinterpret_cast<uint4*>(xb + (size_t)i * 8) = pk.u;
    }
}

// ---------------------------------------------------------------------------
// Kernel 2: Weff_t[n][k] = W[n][k] + SCALE * sum_r A[k][r]*B[r][n], cast bf16.
// ---------------------------------------------------------------------------
__global__ void weff_kernel(const float* __restrict__ W, const float* __restrict__ A,
                            const float* __restrict__ B, bf16_t* __restrict__ Wt) {
    int idx = blockIdx.x * blockDim.x + threadIdx.x;   // DIM_OUT*DIM/32 threads
    int k0 = (idx & 511) << 3;          // 512 k-groups of 8
    int n0 = (idx >> 9) << 2;           // 1024 n-groups of 4

    float bn[4][16];
#pragma unroll
    for (int r = 0; r < 16; ++r) {
        float4 bv = *reinterpret_cast<const float4*>(B + (size_t)r * DIM_OUT + n0);
        bn[0][r] = bv.x; bn[1][r] = bv.y; bn[2][r] = bv.z; bn[3][r] = bv.w;
    }
    float ab[4][8];
#pragma unroll
    for (int j = 0; j < 8; ++j) {
        const float4* ap = reinterpret_cast<const float4*>(A + (size_t)(k0 + j) * LORA_R);
        float4 a0 = ap[0], a1 = ap[1], a2 = ap[2], a3 = ap[3];
        float av[16] = {a0.x,a0.y,a0.z,a0.w,a1.x,a1.y,a1.z,a1.w,
                        a2.x,a2.y,a2.z,a2.w,a3.x,a3.y,a3.z,a3.w};
#pragma unroll
        for (int n = 0; n < 4; ++n) {
            float s = 0.f;
#pragma unroll
            for (int r = 0; r < 16; ++r) s += av[r] * bn[n][r];
            ab[n][j] = s;
        }
    }
#pragma unroll
    for (int n = 0; n < 4; ++n) {
        const float4* wp = reinterpret_cast<const float4*>(W + (size_t)(n0 + n) * DIM + k0);
        float4 w0 = wp[0], w1 = wp[1];
        float wv[8] = {w0.x,w0.y,w0.z,w0.w,w1.x,w1.y,w1.z,w1.w};
        union { bf16_t o[8]; uint4 u; } pk;
#pragma unroll
        for (int j = 0; j < 8; ++j) pk.o[j] = (bf16_t)(wv[j] + LORA_SCALE * ab[n][j]);
        *reinterpret_cast<uint4*>(Wt + (size_t)(n0 + n) * DIM + k0) = pk.u;
    }
}

// ---------------------------------------------------------------------------
// Kernel 3: 256x256 GEMM, snake-order pipelined 4-interval schedule.
// C[m][n] = sum_k Xb[m][k]*Wt[n][k] + bias[n]
// 512 thr = 8 waves (2M x 4N); per-wave 128x64 out = acc[8][4] 16x16 frags.
// LDS: 2 dbuf x (A 256x64 + B 256x64) bf16 = 128 KiB.  Swizzle as round 1
// (verified 0 conflicts): linear LDS + inverse-swizzled global src; ds_read
// col = ((ks*4 + (lane>>4)) ^ (lane&7)) * 8.
//
// Snake quadrants: Q0(m0-3,n0-1) Q1(m0-3,n2-3) Q2(m4-7,n2-3) Q3(m4-7,n0-1).
// Interval = [ds_reads for NEXT quadrant | stage | sched_barrier | 16 MFMA
// of CURRENT quadrant | barrier]  -> LDS pipe overlaps matrix pipe.
//   I0: read bHi(d)           | MFMA Q0 (aLo x bLo)
//   I1: read aHi(d), STAGE_B  | MFMA Q1 (aLo x bHi) | vmcnt(4)
//   I2: read aLo(d^1), STAGE_A| MFMA Q2 (aHi x bHi)
//   I3:                         MFMA Q3 (aHi x bLo) | read bLo(d^1)
// One vmcnt + 4 barriers per K-tile. vmcnt(4) at I1 lands tile t+1's 8 loads
// (issued ~7 intervals earlier -> no stall) before I2/I3 read buffer d^1;
// leaves STAGE_B(t+2)'s 4 loads in flight (never drains to 0).
// Region safety: B(d) last read I0 -> STAGE_B at I1; A(d) last read I1 ->
// STAGE_A at I2; one barrier between each read/write pair.
// ---------------------------------------------------------------------------
#define BM 256
#define BN 256
#define BK 64
#define MB_BLKS (TOKENS / BM)    // 32
#define NB_BLKS (DIM_OUT / BN)   // 16
#define NT      (DIM / BK)       // 64 K-tiles

#define BAR() do { __builtin_amdgcn_s_barrier(); __builtin_amdgcn_sched_barrier(0); } while (0)
#define SB0() __builtin_amdgcn_sched_barrier(0)
#define VMWAIT_(n) asm volatile("s_waitcnt vmcnt(" #n ")" ::: "memory")
#define VMWAIT(n) VMWAIT_(n)

__global__ __launch_bounds__(512, 2) void gemm_kernel(
    const bf16_t* __restrict__ Xb, const bf16_t* __restrict__ Wt,
    const float* __restrict__ bias, float* __restrict__ C)
{
    __shared__ __align__(16) bf16_t sA[2][BM][BK];   // 64 KiB
    __shared__ __align__(16) bf16_t sB[2][BN][BK];   // 64 KiB

    const int nwg = MB_BLKS * NB_BLKS;               // 512, %8==0 -> bijective
    int bid = blockIdx.x;
    int swz = (bid & 7) * (nwg >> 3) + (bid >> 3);   // XCD-aware remap
    int bm = swz / NB_BLKS;
    int bn = swz % NB_BLKS;

    const int tid  = threadIdx.x;
    const int lane = tid & 63;
    const int wid  = tid >> 6;       // 0..7
    const int wr   = wid >> 2;       // 0..1  (M half)
    const int wc   = wid & 3;        // 0..3  (N quarter)

    // ---- staging constants (linear LDS dest, pre-swizzled global src) ----
    const int srow = tid >> 3;                       // 0..63
    const int scol = (tid & 7) * 8;                  // linear col (elems)
    const int koff = (((tid & 7) ^ ((tid >> 3) & 7)) * 8); // swizzled src col
    const bf16_t* Ag = Xb + (size_t)(bm * BM + srow) * DIM + koff;
    const bf16_t* Bg = Wt + (size_t)(bn * BN + srow) * DIM + koff;

#define STAGE_A(d, kt) do { \
    const bf16_t* s_ = Ag + (size_t)(kt) * BK; \
    bf16_t* d_ = &sA[d][srow][scol]; \
    gload_lds16(s_,                     d_); \
    gload_lds16(s_ + (size_t)64  * DIM, d_ + 64  * BK); \
    gload_lds16(s_ + (size_t)128 * DIM, d_ + 128 * BK); \
    gload_lds16(s_ + (size_t)192 * DIM, d_ + 192 * BK); \
} while (0)

#define STAGE_B(d, kt) do { \
    const bf16_t* s_ = Bg + (size_t)(kt) * BK; \
    bf16_t* d_ = &sB[d][srow][scol]; \
    gload_lds16(s_,                     d_); \
    gload_lds16(s_ + (size_t)64  * DIM, d_ + 64  * BK); \
    gload_lds16(s_ + (size_t)128 * DIM, d_ + 128 * BK); \
    gload_lds16(s_ + (size_t)192 * DIM, d_ + 192 * BK); \
} while (0)

    // ---- fragment-read constants (swizzled) ----
    const int q     = lane & 7;
    const int kslot = lane >> 4;                     // 0..3
    const int r15   = lane & 15;
    const int cK0   = ((kslot    ) ^ q) * 8;         // ks=0 col (elems)
    const int cK1   = ((kslot + 4) ^ q) * 8;         // ks=1 col (elems)
    const int arow0 = wr * 128 + r15;                // + m*16
    const int brow0 = wc * 64  + r15;                // + n*16

    f32x4 acc[8][4] = {};
    bfrag aLo[4][2], aHi[4][2], bLo[2][2], bHi[2][2];

#define READ_A4(dst, dd, mb) do { \
    _Pragma("unroll") \
    for (int m_ = 0; m_ < 4; ++m_) { \
        dst[m_][0] = *reinterpret_cast<const bfrag*>(&sA[dd][arow0 + (mb + m_) * 16][cK0]); \
        dst[m_][1] = *reinterpret_cast<const bfrag*>(&sA[dd][arow0 + (mb + m_) * 16][cK1]); \
    } \
} while (0)

#define READ_B2(dst, dd, nb) do { \
    _Pragma("unroll") \
    for (int n_ = 0; n_ < 2; ++n_) { \
        dst[n_][0] = *reinterpret_cast<const bfrag*>(&sB[dd][brow0 + (nb + n_) * 16][cK0]); \
        dst[n_][1] = *reinterpret_cast<const bfrag*>(&sB[dd][brow0 + (nb + n_) * 16][cK1]); \
    } \
} while (0)

#define MFMA_Q(Af, Bf, mb, nb) do { \
    __builtin_amdgcn_s_setprio(1); \
    _Pragma("unroll") \
    for (int m_ = 0; m_ < 4; ++m_) \
    _Pragma("unroll") \
    for (int n_ = 0; n_ < 2; ++n_) \
    _Pragma("unroll") \
    for (int ks_ = 0; ks_ < 2; ++ks_) \
        acc[mb + m_][nb + n_] = __builtin_amdgcn_mfma_f32_16x16x32_bf16( \
            Af[m_][ks_], Bf[n_][ks_], acc[mb + m_][nb + n_], 0, 0, 0); \
    __builtin_amdgcn_s_setprio(0); \
} while (0)

// One K-tile (buffer d). DO_STAGE: stage tile ktn into buffer d.
// DO_NEXT: prefetch next tile's Q0 frags from buffer d^1. VM: vmcnt at I1.
#define TILE(d, ktn, DO_STAGE, DO_NEXT, VM) do { \
    /* I0 */ READ_B2(bHi, d, 2); \
             SB0(); MFMA_Q(aLo, bLo, 0, 0); BAR(); \
    /* I1 */ READ_A4(aHi, d, 4); if (DO_STAGE) STAGE_B(d, ktn); \
             SB0(); MFMA_Q(aLo, bHi, 0, 2); VMWAIT(VM); BAR(); \
    /* I2 */ if (DO_NEXT) READ_A4(aLo, (d) ^ 1, 0); if (DO_STAGE) STAGE_A(d, ktn); \
             SB0(); MFMA_Q(aHi, bHi, 4, 2); BAR(); \
    /* I3 */ MFMA_Q(aHi, bLo, 4, 0); \
             if (DO_NEXT) READ_B2(bLo, (d) ^ 1, 0); BAR(); \
} while (0)

    // ---- prologue: tiles 0,1 staged; tile0's Q0 frags in regs ----
    STAGE_A(0, 0); STAGE_B(0, 0);
    STAGE_B(1, 1); STAGE_A(1, 1);
    VMWAIT(8);          // tile 0 landed; tile 1's 8 loads stay in flight
    BAR();
    READ_A4(aLo, 0, 0); READ_B2(bLo, 0, 0);

    // ---- main loop: 31 iterations x 2 K-tiles, staging t+2 ----
    for (int it = 0; it < NT / 2 - 1; ++it) {
        int kt0 = 2 * it;
        TILE(0, kt0 + 2, true, true, 4);
        TILE(1, kt0 + 3, true, true, 4);
    }
    // ---- peeled tiles 62, 63 ----
    TILE(0, 0, false, true, 0);    // needs tile 63's loads fully landed
    TILE(1, 0, false, false, 0);

    // ---- epilogue: D layout row=(lane>>4)*4+j, col=lane&15 ----
    int row0 = bm * BM + wr * 128 + (lane >> 4) * 4;
    int col0 = bn * BN + wc * 64 + r15;
#pragma unroll
    for (int n = 0; n < 4; ++n) {
        int c = col0 + n * 16;
        float bv = bias[c];
#pragma unroll
        for (int m = 0; m < 8; ++m) {
            int r = row0 + m * 16;
#pragma unroll
            for (int j = 0; j < 4; ++j)
                C[(size_t)(r + j) * DIM_OUT + c] = acc[m][n][j] + bv;
        }
    }
}

// ---------------------------------------------------------------------------
extern "C" void kernel_launch(void* const* d_in, const int* in_sizes, int n_in,
                              void* d_out, int out_size, void* d_ws, size_t ws_size,
                              hipStream_t stream) {
    const float* x = (const float*)d_in[0];
    const float* A = (const float*)d_in[1];
    const float* B = (const float*)d_in[2];
    const float* W = (const float*)d_in[3];
    const float* b = (const float*)d_in[4];
    float* out = (float*)d_out;

    // workspace: xb (8192*4096 bf16 = 64MB) | Wt (4096*4096 bf16 = 32MB)
    bf16_t* xb = (bf16_t*)d_ws;
    bf16_t* Wt = (bf16_t*)((char*)d_ws + (size_t)TOKENS * DIM * 2);

    cast_x_kernel<<<2048, 256, 0, stream>>>(x, xb);
    weff_kernel<<<(DIM_OUT * DIM / 32) / 256, 256, 0, stream>>>(W, A, B, Wt);
    gemm_kernel<<<MB_BLKS * NB_BLKS, 512, 0, stream>>>(xb, Wt, b, out);
}